// Round 10
// baseline (106.568 us; speedup 1.0000x reference)
//
#include <hip/hip_runtime.h>
#include <stdint.h>

#pragma clang fp contract(off)

#define N_ANCH 36864
#define PRE_NMS 1000
#define POST_NMS 300
#define SEL_CAP 1024
#define NWAVE 16

// K1s geometry: 16 slices x B blocks, 256 threads
#define SLICES 16
#define K1_NT 256
#define SLICE_KEYS 2304
#define SLICE_TOP 128                    // exact per-slice top-128
#define CAP2 256                         // compact capacity (= K1_NT)
#define MERGE_CAP 2048

#define NCOPY 8
#define HSTR 257                         // bank-rotating stride per copy

// M layout: column-major per batch — M[word w][row i], word stride 1024
#define M_WSTRIDE 1024
#define M_WORDS_PER_B 16384              // 16*1024 u64 = 128 KB
#define WS_BOX_FLOATS_PER_B 5120

#define K3_NT 512                        // 8 waves: 1 chain + 6 reducers x 2 words

__device__ __forceinline__ uint32_t mono_key(float v) {
    uint32_t u = __float_as_uint(v);
    return (u & 0x80000000u) ? ~u : (u | 0x80000000u);
}

__device__ __forceinline__ float clip01(float x) {
    return fminf(fmaxf(x, 0.0f), 1.0f);
}

__device__ __forceinline__ uint64_t bcast64(uint64_t v, int srclane) {
    uint32_t lo = (uint32_t)v, hi = (uint32_t)(v >> 32);
    lo = __builtin_amdgcn_readlane(lo, srclane);
    hi = __builtin_amdgcn_readlane(hi, srclane);
    return ((uint64_t)hi << 32) | (uint64_t)lo;
}

// Force a (provably wave-uniform) 64-bit value into the scalar domain so the
// greedy bookkeeping compiles to SALU and uniform scalar branches.
__device__ __forceinline__ uint64_t sfl64(uint64_t v) {
    uint32_t lo = __builtin_amdgcn_readfirstlane((uint32_t)v);
    uint32_t hi = __builtin_amdgcn_readfirstlane((uint32_t)(v >> 32));
    return ((uint64_t)hi << 32) | (uint64_t)lo;
}

__device__ __forceinline__ uint64_t bfly_or64(uint64_t v) {
    v |= __shfl_xor(v, 32);
    v |= __shfl_xor(v, 16);
    v |= __shfl_xor(v, 8);
    v |= __shfl_xor(v, 4);
    v |= __shfl_xor(v, 2);
    v |= __shfl_xor(v, 1);
    return v;
}

// 256-bin suffix-rank scan, 256 threads (1 bin each).
__device__ __forceinline__ void scan256(const uint32_t* __restrict__ h, uint32_t K,
                                        uint32_t* shm, uint32_t& outBin, uint32_t& outKrem) {
    const int t    = threadIdx.x;
    const int lane = t & 63;
    const int wv   = t >> 6;             // 4 waves
    const uint32_t q = h[t];
    uint32_t sfx = q, o;
    o = __shfl_down(sfx, 1);  if (lane < 63) sfx += o;
    o = __shfl_down(sfx, 2);  if (lane < 62) sfx += o;
    o = __shfl_down(sfx, 4);  if (lane < 60) sfx += o;
    o = __shfl_down(sfx, 8);  if (lane < 56) sfx += o;
    o = __shfl_down(sfx, 16); if (lane < 48) sfx += o;
    o = __shfl_down(sfx, 32); if (lane < 32) sfx += o;
    if (lane == 0) shm[wv] = sfx;
    __syncthreads();
    uint32_t wAbove = 0;
    for (int w2 = wv + 1; w2 < 4; ++w2) wAbove += shm[w2];
    const uint32_t above = wAbove + (sfx - q);   // keys in bins strictly above mine
    if ((above < K) && (above + q >= K)) { shm[4] = (uint32_t)t; shm[5] = K - above; }
    __syncthreads();
    outBin  = shm[4];
    outKrem = shm[5];
}

// ---------------------------------------------------------------------------
// K1s (R10): fixed-threshold fast path + exact histogram fallback.
//   R10: float4-vectorized label loads (576 f4: f4[t], f4[256+t], wave-0
//   also f4[512+t]; gi = s*2304 + (r>>2)*1024 + 4t + (r&3)) and DYNAMIC
//   rank-loop bound (c+3)&~3 (~192 typical vs 256 fixed).
//   Fast path exactness when count>=128: any key < tau is dominated by
//   >=128 keys, so the true top-128 is inside the compacted set.
// ---------------------------------------------------------------------------
__global__ __launch_bounds__(K1_NT) void k1s_slice_top(
    const float* __restrict__ labels,
    uint64_t* __restrict__ wsCand)      // (B, 16, 128)
{
    const int s = blockIdx.x;
    const int b = blockIdx.y;
    const int t = threadIdx.x;
    const int lane = t & 63;

    __shared__ uint32_t hc[NCOPY * HSTR];   // fallback pass-1 copies
    __shared__ uint32_t red[256];           // fallback pass-1 reduced hist
    __shared__ uint32_t red2[256];          // fallback pass-2 hist
    __shared__ uint32_t shm[8];
    __shared__ uint64_t cand[CAP2];
    __shared__ uint32_t scnt;

    const float* lab = labels + (size_t)b * N_ANCH + (size_t)s * SLICE_KEYS;
    const float4* lf4 = (const float4*)lab;     // 2304 floats = 576 f4, 16B-aligned
    const bool extra = (t < 64);

    uint32_t key[12];
    {
        const float4 v0 = lf4[t];
        const float4 v1 = lf4[256 + t];
        key[0] = mono_key(v0.x); key[1] = mono_key(v0.y);
        key[2] = mono_key(v0.z); key[3] = mono_key(v0.w);
        key[4] = mono_key(v1.x); key[5] = mono_key(v1.y);
        key[6] = mono_key(v1.z); key[7] = mono_key(v1.w);
        if (extra) {
            const float4 v2 = lf4[512 + t];
            key[8]  = mono_key(v2.x); key[9]  = mono_key(v2.y);
            key[10] = mono_key(v2.z); key[11] = mono_key(v2.w);
        } else {
            key[8] = key[9] = key[10] = key[11] = 0u;
        }
    }
    // gi for key[r]: s*2304 + (r>>2)*1024 + 4*t + (r&3)

    for (int i = t; i < NCOPY * HSTR; i += K1_NT) hc[i] = 0u;
    red2[t] = 0u;
    if (t == 0) scnt = 0u;
    __syncthreads();                                            // B1

    // ---- fast-path compact: fixed threshold, wave-aggregated ----
    const uint32_t KTAU = mono_key(0.91666667f);                // const-folded
#pragma unroll
    for (int r = 0; r < 12; ++r) {
        const bool pred = (r < 8 || extra) && (key[r] >= KTAU);
        const uint64_t bal = __ballot(pred ? 1 : 0);
        if (!bal) continue;                  // wave-uniform skip (waves 1-3, r>=8)
        uint32_t base = 0;
        if (lane == 0)
            base = atomicAdd(&scnt, (uint32_t)__popcll(bal));
        base = __shfl(base, 0);
        if (pred) {
            const uint32_t off = (uint32_t)__popcll(bal & ((1ull << lane) - 1ull));
            const uint32_t pos = base + off;
            const uint32_t gi = (uint32_t)(s * SLICE_KEYS + (r >> 2) * 1024 + 4 * t + (r & 3));
            if (pos < CAP2)
                cand[pos] = ((uint64_t)key[r] << 32) | (uint64_t)(0xFFFFFFFFu - gi);
        }
    }
    __syncthreads();                                            // B2
    uint32_t c = scnt;

    if (c < SLICE_TOP || c > CAP2) {
        // ---- exact fallback: two-pass histogram (rare; block-uniform) ----
        if (t == 0) scnt = 0u;
        const int cbase = (lane & 7) * HSTR;
        const int nk = extra ? 12 : 8;      // wave-uniform
        for (int r = 0; r < nk; ++r)
            atomicAdd(&hc[cbase + (key[r] >> 24)], 1u);
        __syncthreads();
        uint32_t sum = 0;
#pragma unroll
        for (int cc = 0; cc < NCOPY; ++cc) sum += hc[cc * HSTR + t];
        red[t] = sum;
        uint32_t b0, krem;
        scan256(red, SLICE_TOP, shm, b0, krem);
        for (int r = 0; r < nk; ++r)
            if ((key[r] >> 24) == b0) atomicAdd(&red2[(key[r] >> 16) & 0xFFu], 1u);
        __syncthreads();
        uint32_t b1, krem2;
        scan256(red2, krem, shm, b1, krem2);
        const uint32_t thresh16 = (b0 << 8) | b1;
#pragma unroll
        for (int r = 0; r < 12; ++r) {
            const bool pred = (r < 8 || extra) && ((key[r] >> 16) >= thresh16);
            const uint64_t bal = __ballot(pred ? 1 : 0);
            if (!bal) continue;
            uint32_t base = 0;
            if (lane == 0)
                base = atomicAdd(&scnt, (uint32_t)__popcll(bal));
            base = __shfl(base, 0);
            if (pred) {
                const uint32_t off = (uint32_t)__popcll(bal & ((1ull << lane) - 1ull));
                const uint32_t pos = base + off;
                const uint32_t gi = (uint32_t)(s * SLICE_KEYS + (r >> 2) * 1024 + 4 * t + (r & 3));
                if (pos < CAP2)
                    cand[pos] = ((uint64_t)key[r] << 32) | (uint64_t)(0xFFFFFFFFu - gi);
            }
        }
        __syncthreads();
        c = scnt; if (c > CAP2) c = CAP2;
    }

    // common tail: pad + exact rank over (c rounded up to 4) entries
    if (t >= (int)c) cand[t] = 0ull;        // pad (never beats real)
    __syncthreads();                                            // B3

    const uint64_t mine = cand[t];
    const uint32_t cu = (c + 3u) & ~3u;     // wave-uniform dynamic bound
    uint32_t rank = 0;
    for (uint32_t i = 0; i < cu; i += 4)
        rank += (cand[i]     > mine) + (cand[i + 1] > mine)
              + (cand[i + 2] > mine) + (cand[i + 3] > mine);
    if (t < (int)c && rank < SLICE_TOP)
        wsCand[((size_t)b * SLICES + s) * SLICE_TOP + rank] = mine;
}

// ---------------------------------------------------------------------------
// K1m (R9, unchanged): paired round-major search. Each key ranked by a LANE
//   PAIR: even lane runs 0-7, odd lane runs 8-15, combined via shfl_xor.
// ---------------------------------------------------------------------------
__global__ __launch_bounds__(K1_NT) void k1m_merge_decode(
    const float* __restrict__ deltas,
    const float* __restrict__ anchors,
    const uint64_t* __restrict__ wsCand,
    float* __restrict__ wsBox)
{
    const int chunk = blockIdx.x;
    const int b     = blockIdx.y;
    const int t     = threadIdx.x;

    __shared__ __align__(16) uint64_t keyA[MERGE_CAP];
    const uint4* c4 = (const uint4*)(wsCand + (size_t)b * MERGE_CAP);
    uint4* k4 = (uint4*)keyA;
#pragma unroll
    for (int i = t; i < MERGE_CAP / 2; i += K1_NT) k4[i] = c4[i];
    __syncthreads();

    const int p    = t >> 1;         // key index 0..127
    const int half = t & 1;          // run-group selector
    const uint64_t mine = keyA[chunk * SLICE_TOP + p];
    uint32_t lo[8];
#pragma unroll
    for (int r = 0; r < 8; ++r) lo[r] = 0u;
    const int rbase = half * 8;

#pragma unroll
    for (uint32_t s2 = 128; s2 > 0; s2 >>= 1) {
        uint64_t probe[8];
#pragma unroll
        for (int r = 0; r < 8; ++r) {
            const uint32_t idx = lo[r] + s2 - 1u;       // valid iff idx < 128
            probe[r] = keyA[(rbase + r) * SLICE_TOP + (idx < 128u ? idx : 0u)];
        }
#pragma unroll
        for (int r = 0; r < 8; ++r) {
            const uint32_t idx = lo[r] + s2 - 1u;
            if (idx < 128u && probe[r] > mine) lo[r] += s2;
        }
    }
    uint32_t rank8 = 0;
#pragma unroll
    for (int r = 0; r < 8; ++r) rank8 += lo[r];
    const uint32_t rank = rank8 + __shfl_xor(rank8, 1);

    if (half == 0 && rank < PRE_NMS) {
        uint32_t idx = 0xFFFFFFFFu - (uint32_t)(mine & 0xFFFFFFFFull);
        float4 d4 = *(const float4*)(deltas + ((size_t)b * N_ANCH + idx) * 4);
        float4 a4 = *(const float4*)(anchors + (size_t)idx * 4);
        float anc_h  = a4.z - a4.x;
        float anc_w  = a4.w - a4.y;
        float anc_cy = a4.x + 0.5f * anc_h;
        float anc_cx = a4.y + 0.5f * anc_w;
        float dy = d4.x * 0.1f, dx = d4.y * 0.1f;
        float dh = d4.z * 0.2f, dw = d4.w * 0.2f;
        float h  = expf(dh) * anc_h;
        float w  = expf(dw) * anc_w;
        float cy = dy * anc_h + anc_cy;
        float cx = dx * anc_w + anc_cx;
        float y1 = cy - 0.5f * h, x1 = cx - 0.5f * w;
        float y2 = cy + 0.5f * h, x2 = cx + 0.5f * w;
        float* wb = wsBox + (size_t)b * WS_BOX_FLOATS_PER_B;
        wb[rank]              = y1;
        wb[SEL_CAP + rank]    = x1;
        wb[2*SEL_CAP + rank]  = y2;
        wb[3*SEL_CAP + rank]  = x2;
        wb[4*SEL_CAP + rank]  = (y2 - y1) * (x2 - x1);
    }
}

// ---------------------------------------------------------------------------
// K2: suppression matrix, column-major M[word][row], load-balanced.
//     grid (24, B): gx<16: cb=gx, rows [0, min(512,64(cb+1)));
//                   gx>=16: cb=gx-8, rows [512, 64(cb+1)).
//     Garbage columns >= 1000 land in word-15 bits >= 40 (masked in K3).
// ---------------------------------------------------------------------------
__global__ __launch_bounds__(1024) void k2_iou_matrix(
    const float* __restrict__ wsBox,
    uint64_t* __restrict__ wsM)
{
    const int gx   = blockIdx.x;
    const int b    = blockIdx.y;
    const int t    = threadIdx.x;
    const int lane = t & 63;
    const int wave = t >> 6;

    int cb, r0, r1;
    if (gx < 16) { cb = gx;     r0 = 0;   r1 = 64 * (cb + 1); if (r1 > 512) r1 = 512; }
    else         { cb = gx - 8; r0 = 512; r1 = 64 * (cb + 1); }
    if (r1 > PRE_NMS) r1 = PRE_NMS;

    __shared__ float s[5 * SEL_CAP];
    const float4* b4 = (const float4*)(wsBox + (size_t)b * WS_BOX_FLOATS_PER_B);
    float4* s4 = (float4*)s;
    for (int i = t; i < (5 * SEL_CAP) / 4; i += 1024) s4[i] = b4[i];
    __syncthreads();

    float* ly1 = s;
    float* lx1 = s + SEL_CAP;
    float* ly2 = s + 2 * SEL_CAP;
    float* lx2 = s + 3 * SEL_CAP;
    float* lar = s + 4 * SEL_CAP;

    const int j = cb * 64 + lane;
    const float y1j = ly1[j], x1j = lx1[j], y2j = ly2[j], x2j = lx2[j], aj = lar[j];

    uint64_t* Mb = wsM + (size_t)b * M_WORDS_PER_B + (size_t)cb * M_WSTRIDE;
    for (int i = r0 + wave; i < r1; i += NWAVE) {
        float iy1 = fmaxf(ly1[i], y1j);
        float ix1 = fmaxf(lx1[i], x1j);
        float iy2 = fminf(ly2[i], y2j);
        float ix2 = fminf(lx2[i], x2j);
        float ih = iy2 - iy1; if (ih < 0.f) ih = 0.f;
        float iw = ix2 - ix1; if (iw < 0.f) iw = 0.f;
        float inter = ih * iw;
        float denom = lar[i] + aj - inter;
        if (denom < 1e-9f) denom = 1e-9f;
        float iou = inter / denom;            // IEEE divide: match numpy bits
        bool sup = (j > i) && (iou > 0.7f);
        uint64_t mask = __ballot(sup ? 1 : 0);
        if (lane == 0) Mb[i] = mask;
    }
}

// ---------------------------------------------------------------------------
// K3 (R10): 8-phase greedy NMS (R8 structure). R10: output zero-fill issued
//   at kernel START so the 1.2K stores drain under the 8 phases (the
//   pre-gather __syncthreads drains vmcnt, ordering them before the
//   rank-scatter overwrites).
// ---------------------------------------------------------------------------
__global__ __launch_bounds__(K3_NT) void k3_reduce_out(
    const float* __restrict__ wsBox,
    const uint64_t* __restrict__ wsM,
    float* __restrict__ out)
{
    const int b    = blockIdx.x;
    const int t    = threadIdx.x;
    const int lane = t & 63;
    const int wave = t >> 6;

    __shared__ uint64_t remv[16];
    __shared__ uint64_t keepW[16];
    __shared__ uint32_t wordPref[16];

    const uint64_t* Mg = wsM + (size_t)b * M_WORDS_PER_B;

    // zero-fill output NOW -- drains under the phase loop
    float* ob = out + (size_t)b * (POST_NMS * 4);
    for (int i = t; i < POST_NMS * 4; i += K3_NT) ob[i] = 0.0f;

    if (t < 16) remv[t] = 0ull;

    // prefetch phase-0 operands
    uint64_t dA = 0, dB = 0, sAB = 0, brA2 = 0, brB2 = 0, brA3 = 0, brB3 = 0;
    uint64_t mA1 = 0, mB1 = 0, mA2 = 0, mB2 = 0;
    if (wave == 0) {
        dA   = Mg[lane];                                   // M[0][rows 0]
        dB   = Mg[(size_t)1 * M_WSTRIDE + 64 + lane];      // M[1][rows 1]
        sAB  = Mg[(size_t)1 * M_WSTRIDE + lane];           // M[1][rows 0]
        brA2 = Mg[(size_t)2 * M_WSTRIDE + lane];           // M[2][rows 0]
        brB2 = Mg[(size_t)2 * M_WSTRIDE + 64 + lane];      // M[2][rows 1]
        brA3 = Mg[(size_t)3 * M_WSTRIDE + lane];           // M[3][rows 0]
        brB3 = Mg[(size_t)3 * M_WSTRIDE + 64 + lane];      // M[3][rows 1]
    } else if (wave <= 6) {
        const int v1 = 2 * wave + 2, v2 = 2 * wave + 3;
        mA1 = Mg[(size_t)v1 * M_WSTRIDE + lane];           // M[v1][rows 0]
        mB1 = Mg[(size_t)v1 * M_WSTRIDE + 64 + lane];      // M[v1][rows 1]
        mA2 = Mg[(size_t)v2 * M_WSTRIDE + lane];
        mB2 = Mg[(size_t)v2 * M_WSTRIDE + 64 + lane];
    }
    uint64_t bridgeA = 0ull, bridgeB = 0ull;
    __syncthreads();

    for (int p = 0; p < 8; ++p) {
        if (wave == 0) {
            const int a = 2 * p, bw = 2 * p + 1;
            const uint64_t mda = dA, mdb = dB, msab = sAB;
            const uint64_t b2a = brA2, b2b = brB2, b3a = brA3, b3b = brB3;
            // prefetch phase p+1 operands (addresses independent of keeps)
            if (p < 7) {
                const int an = 2 * p + 2, bn = 2 * p + 3;
                dA  = Mg[(size_t)an * M_WSTRIDE + 64 * an + lane];
                dB  = Mg[(size_t)bn * M_WSTRIDE + 64 * bn + lane];
                sAB = Mg[(size_t)bn * M_WSTRIDE + 64 * an + lane];
                if (p < 6) {
                    const int a3 = 2 * p + 4, b3 = 2 * p + 5;
                    brA2 = Mg[(size_t)a3 * M_WSTRIDE + 64 * an + lane];
                    brB2 = Mg[(size_t)a3 * M_WSTRIDE + 64 * bn + lane];
                    brA3 = Mg[(size_t)b3 * M_WSTRIDE + 64 * an + lane];
                    brB3 = Mg[(size_t)b3 * M_WSTRIDE + 64 * bn + lane];
                }
            }
            // ---- word a (a <= 14, always fully valid) ----
            uint64_t curA = sfl64(remv[a]) | sfl64(bridgeA);
            {
                const uint64_t amS = sfl64(bfly_or64(mda));
                const uint64_t Q        = amS & ~curA;
                const uint64_t keptSure = ~curA & ~Q;
                curA |= sfl64(bfly_or64(((keptSure >> lane) & 1ull) ? mda : 0ull));
                uint64_t work = Q & ~curA;
                while (work) {
                    const int bp = (int)__builtin_ctzll(work);
                    curA |= bcast64(mda, bp);
                    work &= ~(1ull << bp);
                    work &= ~curA;
                }
            }
            const uint64_t keepA = ~curA;
            // in-phase bridge a -> bw
            const uint64_t sc = bfly_or64(((keepA >> lane) & 1ull) ? msab : 0ull);
            // ---- word bw ----
            const uint64_t validB = (bw == 15) ? ((1ull << 40) - 1ull) : ~0ull;
            uint64_t curB = sfl64(remv[bw]) | sfl64(bridgeB) | sfl64(sc);
            {
                const bool lv = (bw < 15) || (lane < 40);
                const uint64_t amS = sfl64(bfly_or64(lv ? mdb : 0ull));
                const uint64_t Q        = amS & ~curB & validB;
                const uint64_t keptSure = validB & ~curB & ~Q;
                curB |= sfl64(bfly_or64(((keptSure >> lane) & 1ull) ? mdb : 0ull));
                uint64_t work = Q & ~curB;
                while (work) {
                    const int bp = (int)__builtin_ctzll(work);
                    curB |= bcast64(mdb, bp);
                    work &= ~(1ull << bp);
                    work &= ~curB;
                }
            }
            const uint64_t keepB = (~curB) & validB;
            if (lane == 0) { keepW[a] = keepA; keepW[bw] = keepB; }
            // bridges for phase p+1 (u in {a,bw} -> v in {2p+2, 2p+3})
            if (p < 7) {
                bridgeA = bfly_or64((((keepA >> lane) & 1ull) ? b2a : 0ull) |
                                    (((keepB >> lane) & 1ull) ? b2b : 0ull));
                bridgeB = bfly_or64((((keepA >> lane) & 1ull) ? b3a : 0ull) |
                                    (((keepB >> lane) & 1ull) ? b3b : 0ull));
            }
        } else if (wave <= 6 && p >= 1 && p <= wave) {
            const int v1 = 2 * wave + 2, v2 = 2 * wave + 3;
            const uint64_t a1 = mA1, b1 = mB1, a2 = mA2, b2 = mB2;
            // prefetch phase p+1 operands: rows-blocks 2p, 2p+1
            if (p < wave) {
                mA1 = Mg[(size_t)v1 * M_WSTRIDE + 64 * (2 * p)     + lane];
                mB1 = Mg[(size_t)v1 * M_WSTRIDE + 64 * (2 * p + 1) + lane];
                mA2 = Mg[(size_t)v2 * M_WSTRIDE + 64 * (2 * p)     + lane];
                mB2 = Mg[(size_t)v2 * M_WSTRIDE + 64 * (2 * p + 1) + lane];
            }
            const uint64_t kmA = keepW[2 * p - 2];         // uniform
            const uint64_t kmB = keepW[2 * p - 1];         // uniform
            uint64_t x1 = (((kmA >> lane) & 1ull) ? a1 : 0ull) |
                          (((kmB >> lane) & 1ull) ? b1 : 0ull);
            x1 = bfly_or64(x1);
            uint64_t x2 = (((kmA >> lane) & 1ull) ? a2 : 0ull) |
                          (((kmB >> lane) & 1ull) ? b2 : 0ull);
            x2 = bfly_or64(x2);
            if (lane == 0) { remv[v1] |= x1; remv[v2] |= x2; }
        }
        __syncthreads();
    }

    if (t == 0) {
        uint32_t acc = 0u;
        for (int w = 0; w < 16; ++w) {
            wordPref[w] = acc;
            acc += (uint32_t)__popcll(keepW[w]);
        }
    }
    __syncthreads();   // orders wordPref write AND drains the zero-fill stores

    for (int tt = t; tt < PRE_NMS; tt += K3_NT) {
        const int w = tt >> 6, bpos = tt & 63;
        uint64_t kw = keepW[w];
        if ((kw >> bpos) & 1ull) {
            uint32_t rank = wordPref[w] +
                            (uint32_t)__popcll(kw & ((1ull << bpos) - 1ull));
            if (rank < POST_NMS) {
                const float* wb = wsBox + (size_t)b * WS_BOX_FLOATS_PER_B;
                float* o = ob + (size_t)rank * 4;
                o[0] = clip01(wb[tt]);
                o[1] = clip01(wb[SEL_CAP + tt]);
                o[2] = clip01(wb[2*SEL_CAP + tt]);
                o[3] = clip01(wb[3*SEL_CAP + tt]);
            }
        }
    }
}

extern "C" void kernel_launch(void* const* d_in, const int* in_sizes, int n_in,
                              void* d_out, int out_size, void* d_ws, size_t ws_size,
                              hipStream_t stream) {
    const float* deltas  = (const float*)d_in[0];
    const float* labels  = (const float*)d_in[1];
    const float* anchors = (const float*)d_in[2];
    float* out = (float*)d_out;
    const int B = in_sizes[1] / N_ANCH;   // 16

    // ws: [cand (B,16,128) u64][box (B,5,1024) f32][M (B,16,1024) u64]
    char* p = (char*)d_ws;
    uint64_t* wsCand = (uint64_t*)p;
    float*    wsBox  = (float*)(p + (size_t)B * MERGE_CAP * 8);
    uint64_t* wsM    = (uint64_t*)(p + (size_t)B * MERGE_CAP * 8
                                     + (size_t)B * WS_BOX_FLOATS_PER_B * 4);

    k1s_slice_top<<<dim3(SLICES, B), K1_NT, 0, stream>>>(labels, wsCand);
    k1m_merge_decode<<<dim3(SLICES, B), K1_NT, 0, stream>>>(deltas, anchors, wsCand, wsBox);
    k2_iou_matrix<<<dim3(24, B), 1024, 0, stream>>>(wsBox, wsM);
    k3_reduce_out<<<B, K3_NT, 0, stream>>>(wsBox, wsM, out);
}

// Round 11
// 105.546 us; speedup vs baseline: 1.0097x; 1.0097x over previous
//
#include <hip/hip_runtime.h>
#include <stdint.h>

#pragma clang fp contract(off)

#define N_ANCH 36864
#define PRE_NMS 1000
#define POST_NMS 300
#define SEL_CAP 1024
#define NWAVE 16

// K1s geometry: 16 slices x B blocks, 256 threads, 9 keys/thread
#define SLICES 16
#define K1_NT 256
#define SLICE_KEYS 2304
#define KEYS_PT 9
#define SLICE_TOP 128                    // exact per-slice top-128
#define CAP2 256                         // compact capacity (= K1_NT)
#define MERGE_CAP 2048

#define NCOPY 8
#define HSTR 257                         // bank-rotating stride per copy

// M layout: column-major per batch — M[word w][row i], word stride 1024
#define M_WSTRIDE 1024
#define M_WORDS_PER_B 16384              // 16*1024 u64 = 128 KB
#define WS_BOX_FLOATS_PER_B 5120

#define K3_NT 512                        // 8 waves: 1 chain + 6 reducers x 2 words

__device__ __forceinline__ uint32_t mono_key(float v) {
    uint32_t u = __float_as_uint(v);
    return (u & 0x80000000u) ? ~u : (u | 0x80000000u);
}

__device__ __forceinline__ float clip01(float x) {
    return fminf(fmaxf(x, 0.0f), 1.0f);
}

__device__ __forceinline__ uint64_t bcast64(uint64_t v, int srclane) {
    uint32_t lo = (uint32_t)v, hi = (uint32_t)(v >> 32);
    lo = __builtin_amdgcn_readlane(lo, srclane);
    hi = __builtin_amdgcn_readlane(hi, srclane);
    return ((uint64_t)hi << 32) | (uint64_t)lo;
}

// Force a (provably wave-uniform) 64-bit value into the scalar domain so the
// greedy bookkeeping compiles to SALU and uniform scalar branches.
__device__ __forceinline__ uint64_t sfl64(uint64_t v) {
    uint32_t lo = __builtin_amdgcn_readfirstlane((uint32_t)v);
    uint32_t hi = __builtin_amdgcn_readfirstlane((uint32_t)(v >> 32));
    return ((uint64_t)hi << 32) | (uint64_t)lo;
}

__device__ __forceinline__ uint64_t bfly_or64(uint64_t v) {
    v |= __shfl_xor(v, 32);
    v |= __shfl_xor(v, 16);
    v |= __shfl_xor(v, 8);
    v |= __shfl_xor(v, 4);
    v |= __shfl_xor(v, 2);
    v |= __shfl_xor(v, 1);
    return v;
}

// 256-bin suffix-rank scan, 256 threads (1 bin each). Finds bin s.t.
// count(bins > bin) < K <= count(bins >= bin); krem = K - count(bins > bin).
// NOTE: no barrier required between writing h[t] (own index) and calling this
// (first read is h[own t]); internal barriers cover shm.
__device__ __forceinline__ void scan256(const uint32_t* __restrict__ h, uint32_t K,
                                        uint32_t* shm, uint32_t& outBin, uint32_t& outKrem) {
    const int t    = threadIdx.x;
    const int lane = t & 63;
    const int wv   = t >> 6;             // 4 waves
    const uint32_t q = h[t];
    uint32_t sfx = q, o;
    o = __shfl_down(sfx, 1);  if (lane < 63) sfx += o;
    o = __shfl_down(sfx, 2);  if (lane < 62) sfx += o;
    o = __shfl_down(sfx, 4);  if (lane < 60) sfx += o;
    o = __shfl_down(sfx, 8);  if (lane < 56) sfx += o;
    o = __shfl_down(sfx, 16); if (lane < 48) sfx += o;
    o = __shfl_down(sfx, 32); if (lane < 32) sfx += o;
    if (lane == 0) shm[wv] = sfx;
    __syncthreads();
    uint32_t wAbove = 0;
    for (int w2 = wv + 1; w2 < 4; ++w2) wAbove += shm[w2];
    const uint32_t above = wAbove + (sfx - q);   // keys in bins strictly above mine
    if ((above < K) && (above + q >= K)) { shm[4] = (uint32_t)t; shm[5] = K - above; }
    __syncthreads();
    outBin  = shm[4];
    outKrem = shm[5];
}

// ---------------------------------------------------------------------------
// K1s (R9 best): fixed-threshold fast path + exact histogram fallback.
//   Labels ~ U[0,1): the 192nd-of-2304 quantile is ~0.9167 (sigma ~13.3
//   keys). Fast path: compact key >= mono_key(0.9167) (wave-aggregated,
//   CAP2=256), 3 barriers, no histogram. If count outside [128, 256]
//   (~4.8 sigma, P~4e-4 over all blocks), run the exact 2-pass histogram
//   fallback — correctness is input-independent; the threshold only
//   selects the fast branch. Exactness when count>=128: any key < tau is
//   dominated by >=128 keys, so top-128 is inside the compacted set.
// ---------------------------------------------------------------------------
__global__ __launch_bounds__(K1_NT) void k1s_slice_top(
    const float* __restrict__ labels,
    uint64_t* __restrict__ wsCand)      // (B, 16, 128)
{
    const int s = blockIdx.x;
    const int b = blockIdx.y;
    const int t = threadIdx.x;
    const int lane = t & 63;

    __shared__ uint32_t hc[NCOPY * HSTR];   // fallback pass-1 copies
    __shared__ uint32_t red[256];           // fallback pass-1 reduced hist
    __shared__ uint32_t red2[256];          // fallback pass-2 hist
    __shared__ uint32_t shm[8];
    __shared__ uint64_t cand[CAP2];
    __shared__ uint32_t scnt;

    const float* lab = labels + (size_t)b * N_ANCH + (size_t)s * SLICE_KEYS;
    uint32_t key[KEYS_PT];
#pragma unroll
    for (int r = 0; r < KEYS_PT; ++r)
        key[r] = mono_key(lab[r * K1_NT + t]);

    for (int i = t; i < NCOPY * HSTR; i += K1_NT) hc[i] = 0u;
    red2[t] = 0u;
    if (t == 0) scnt = 0u;
    __syncthreads();                                            // B1

    // ---- fast-path compact: fixed threshold, wave-aggregated ----
    const uint32_t KTAU = mono_key(0.91666667f);                // const-folded
#pragma unroll
    for (int r = 0; r < KEYS_PT; ++r) {
        const uint32_t u = key[r];
        const bool pred = (u >= KTAU);
        const uint64_t bal = __ballot(pred ? 1 : 0);
        uint32_t base = 0;
        if (lane == 0 && bal)
            base = atomicAdd(&scnt, (uint32_t)__popcll(bal));
        base = __shfl(base, 0);
        if (pred) {
            const uint32_t off = (uint32_t)__popcll(bal & ((1ull << lane) - 1ull));
            const uint32_t pos = base + off;
            const uint32_t gi = (uint32_t)(s * SLICE_KEYS + r * K1_NT + t);
            if (pos < CAP2)
                cand[pos] = ((uint64_t)u << 32) | (uint64_t)(0xFFFFFFFFu - gi);
        }
    }
    __syncthreads();                                            // B2
    uint32_t c = scnt;

    if (c < SLICE_TOP || c > CAP2) {
        // ---- exact fallback: two-pass histogram (rare; block-uniform) ----
        if (t == 0) scnt = 0u;
        const int cbase = (lane & 7) * HSTR;
#pragma unroll
        for (int r = 0; r < KEYS_PT; ++r)
            atomicAdd(&hc[cbase + (key[r] >> 24)], 1u);
        __syncthreads();
        uint32_t sum = 0;
#pragma unroll
        for (int cc = 0; cc < NCOPY; ++cc) sum += hc[cc * HSTR + t];
        red[t] = sum;
        uint32_t b0, krem;
        scan256(red, SLICE_TOP, shm, b0, krem);
#pragma unroll
        for (int r = 0; r < KEYS_PT; ++r)
            if ((key[r] >> 24) == b0) atomicAdd(&red2[(key[r] >> 16) & 0xFFu], 1u);
        __syncthreads();
        uint32_t b1, krem2;
        scan256(red2, krem, shm, b1, krem2);
        const uint32_t thresh16 = (b0 << 8) | b1;
#pragma unroll
        for (int r = 0; r < KEYS_PT; ++r) {
            const uint32_t u = key[r];
            const bool pred = (u >> 16) >= thresh16;
            const uint64_t bal = __ballot(pred ? 1 : 0);
            uint32_t base = 0;
            if (lane == 0 && bal)
                base = atomicAdd(&scnt, (uint32_t)__popcll(bal));
            base = __shfl(base, 0);
            if (pred) {
                const uint32_t off = (uint32_t)__popcll(bal & ((1ull << lane) - 1ull));
                const uint32_t pos = base + off;
                const uint32_t gi = (uint32_t)(s * SLICE_KEYS + r * K1_NT + t);
                if (pos < CAP2)
                    cand[pos] = ((uint64_t)u << 32) | (uint64_t)(0xFFFFFFFFu - gi);
            }
        }
        __syncthreads();
        c = scnt; if (c > CAP2) c = CAP2;
    }

    // common tail: pad + exact rank over CAP2 entries
    if (t >= (int)c) cand[t] = 0ull;        // pad (never beats real)
    __syncthreads();                                            // B3

    const uint64_t mine = cand[t];
    uint32_t rank = 0;
    for (int i = 0; i < CAP2; i += 4)
        rank += (cand[i]     > mine) + (cand[i + 1] > mine)
              + (cand[i + 2] > mine) + (cand[i + 3] > mine);
    if (t < (int)c && rank < SLICE_TOP)
        wsCand[((size_t)b * SLICES + s) * SLICE_TOP + rank] = mine;
}

// ---------------------------------------------------------------------------
// K1m (R9 best): paired round-major search. Each key is ranked by a LANE
//   PAIR: even lane handles runs 0-7, odd lane runs 8-15 (8 probes/round),
//   combined via __shfl_xor(rank,1). All 256 threads active; 7 dependent
//   rounds (latency term) unchanged, per-round issue work halved.
// ---------------------------------------------------------------------------
__global__ __launch_bounds__(K1_NT) void k1m_merge_decode(
    const float* __restrict__ deltas,
    const float* __restrict__ anchors,
    const uint64_t* __restrict__ wsCand,
    float* __restrict__ wsBox)
{
    const int chunk = blockIdx.x;
    const int b     = blockIdx.y;
    const int t     = threadIdx.x;

    __shared__ __align__(16) uint64_t keyA[MERGE_CAP];
    const uint4* c4 = (const uint4*)(wsCand + (size_t)b * MERGE_CAP);
    uint4* k4 = (uint4*)keyA;
#pragma unroll
    for (int i = t; i < MERGE_CAP / 2; i += K1_NT) k4[i] = c4[i];
    __syncthreads();

    const int p    = t >> 1;         // key index 0..127
    const int half = t & 1;          // run-group selector
    const uint64_t mine = keyA[chunk * SLICE_TOP + p];
    uint32_t lo[8];
#pragma unroll
    for (int r = 0; r < 8; ++r) lo[r] = 0u;
    const int rbase = half * 8;

#pragma unroll
    for (uint32_t s2 = 128; s2 > 0; s2 >>= 1) {
        uint64_t probe[8];
#pragma unroll
        for (int r = 0; r < 8; ++r) {
            const uint32_t idx = lo[r] + s2 - 1u;       // valid iff idx < 128
            probe[r] = keyA[(rbase + r) * SLICE_TOP + (idx < 128u ? idx : 0u)];
        }
#pragma unroll
        for (int r = 0; r < 8; ++r) {
            const uint32_t idx = lo[r] + s2 - 1u;
            if (idx < 128u && probe[r] > mine) lo[r] += s2;
        }
    }
    uint32_t rank8 = 0;
#pragma unroll
    for (int r = 0; r < 8; ++r) rank8 += lo[r];
    const uint32_t rank = rank8 + __shfl_xor(rank8, 1);

    if (half == 0 && rank < PRE_NMS) {
        uint32_t idx = 0xFFFFFFFFu - (uint32_t)(mine & 0xFFFFFFFFull);
        float4 d4 = *(const float4*)(deltas + ((size_t)b * N_ANCH + idx) * 4);
        float4 a4 = *(const float4*)(anchors + (size_t)idx * 4);
        float anc_h  = a4.z - a4.x;
        float anc_w  = a4.w - a4.y;
        float anc_cy = a4.x + 0.5f * anc_h;
        float anc_cx = a4.y + 0.5f * anc_w;
        float dy = d4.x * 0.1f, dx = d4.y * 0.1f;
        float dh = d4.z * 0.2f, dw = d4.w * 0.2f;
        float h  = expf(dh) * anc_h;
        float w  = expf(dw) * anc_w;
        float cy = dy * anc_h + anc_cy;
        float cx = dx * anc_w + anc_cx;
        float y1 = cy - 0.5f * h, x1 = cx - 0.5f * w;
        float y2 = cy + 0.5f * h, x2 = cx + 0.5f * w;
        float* wb = wsBox + (size_t)b * WS_BOX_FLOATS_PER_B;
        wb[rank]              = y1;
        wb[SEL_CAP + rank]    = x1;
        wb[2*SEL_CAP + rank]  = y2;
        wb[3*SEL_CAP + rank]  = x2;
        wb[4*SEL_CAP + rank]  = (y2 - y1) * (x2 - x1);
    }
}

// ---------------------------------------------------------------------------
// K2: suppression matrix, column-major M[word][row], load-balanced.
//     grid (24, B): gx<16: cb=gx, rows [0, min(512,64(cb+1)));
//                   gx>=16: cb=gx-8, rows [512, 64(cb+1)).
//     Garbage columns >= 1000 land in word-15 bits >= 40 (masked in K3).
// ---------------------------------------------------------------------------
__global__ __launch_bounds__(1024) void k2_iou_matrix(
    const float* __restrict__ wsBox,
    uint64_t* __restrict__ wsM)
{
    const int gx   = blockIdx.x;
    const int b    = blockIdx.y;
    const int t    = threadIdx.x;
    const int lane = t & 63;
    const int wave = t >> 6;

    int cb, r0, r1;
    if (gx < 16) { cb = gx;     r0 = 0;   r1 = 64 * (cb + 1); if (r1 > 512) r1 = 512; }
    else         { cb = gx - 8; r0 = 512; r1 = 64 * (cb + 1); }
    if (r1 > PRE_NMS) r1 = PRE_NMS;

    __shared__ float s[5 * SEL_CAP];
    const float4* b4 = (const float4*)(wsBox + (size_t)b * WS_BOX_FLOATS_PER_B);
    float4* s4 = (float4*)s;
    for (int i = t; i < (5 * SEL_CAP) / 4; i += 1024) s4[i] = b4[i];
    __syncthreads();

    float* ly1 = s;
    float* lx1 = s + SEL_CAP;
    float* ly2 = s + 2 * SEL_CAP;
    float* lx2 = s + 3 * SEL_CAP;
    float* lar = s + 4 * SEL_CAP;

    const int j = cb * 64 + lane;
    const float y1j = ly1[j], x1j = lx1[j], y2j = ly2[j], x2j = lx2[j], aj = lar[j];

    uint64_t* Mb = wsM + (size_t)b * M_WORDS_PER_B + (size_t)cb * M_WSTRIDE;
    for (int i = r0 + wave; i < r1; i += NWAVE) {
        float iy1 = fmaxf(ly1[i], y1j);
        float ix1 = fmaxf(lx1[i], x1j);
        float iy2 = fminf(ly2[i], y2j);
        float ix2 = fminf(lx2[i], x2j);
        float ih = iy2 - iy1; if (ih < 0.f) ih = 0.f;
        float iw = ix2 - ix1; if (iw < 0.f) iw = 0.f;
        float inter = ih * iw;
        float denom = lar[i] + aj - inter;
        if (denom < 1e-9f) denom = 1e-9f;
        float iou = inter / denom;            // IEEE divide: match numpy bits
        bool sup = (j > i) && (iou > 0.7f);
        uint64_t mask = __ballot(sup ? 1 : 0);
        if (lane == 0) Mb[i] = mask;
    }
}

// ---------------------------------------------------------------------------
// K3 (R8 structure, R9 best): greedy NMS with EIGHT phases (2 words/phase).
//   Coverage of pair (u < v), exactly once:
//     same word           : in-word sparse chain
//     same phase (2p,2p+1): in-register selfC butterfly (sc)
//     adjacent phase      : wave0 "bridges" computed at END of phase p-1
//     gap >= 2 phases     : reducer at phase q applies keepW[2q-2],keepW[2q-1]
//   Reducer wave r (1..6) owns words {2r+2, 2r+3}, active phases 1..r.
//   All M loads prefetched one phase ahead.
// ---------------------------------------------------------------------------
__global__ __launch_bounds__(K3_NT) void k3_reduce_out(
    const float* __restrict__ wsBox,
    const uint64_t* __restrict__ wsM,
    float* __restrict__ out)
{
    const int b    = blockIdx.x;
    const int t    = threadIdx.x;
    const int lane = t & 63;
    const int wave = t >> 6;

    __shared__ uint64_t remv[16];
    __shared__ uint64_t keepW[16];
    __shared__ uint32_t wordPref[16];

    const uint64_t* Mg = wsM + (size_t)b * M_WORDS_PER_B;

    if (t < 16) remv[t] = 0ull;

    // prefetch phase-0 operands
    uint64_t dA = 0, dB = 0, sAB = 0, brA2 = 0, brB2 = 0, brA3 = 0, brB3 = 0;
    uint64_t mA1 = 0, mB1 = 0, mA2 = 0, mB2 = 0;
    if (wave == 0) {
        dA   = Mg[lane];                                   // M[0][rows 0]
        dB   = Mg[(size_t)1 * M_WSTRIDE + 64 + lane];      // M[1][rows 1]
        sAB  = Mg[(size_t)1 * M_WSTRIDE + lane];           // M[1][rows 0]
        brA2 = Mg[(size_t)2 * M_WSTRIDE + lane];           // M[2][rows 0]
        brB2 = Mg[(size_t)2 * M_WSTRIDE + 64 + lane];      // M[2][rows 1]
        brA3 = Mg[(size_t)3 * M_WSTRIDE + lane];           // M[3][rows 0]
        brB3 = Mg[(size_t)3 * M_WSTRIDE + 64 + lane];      // M[3][rows 1]
    } else if (wave <= 6) {
        const int v1 = 2 * wave + 2, v2 = 2 * wave + 3;
        mA1 = Mg[(size_t)v1 * M_WSTRIDE + lane];           // M[v1][rows 0]
        mB1 = Mg[(size_t)v1 * M_WSTRIDE + 64 + lane];      // M[v1][rows 1]
        mA2 = Mg[(size_t)v2 * M_WSTRIDE + lane];
        mB2 = Mg[(size_t)v2 * M_WSTRIDE + 64 + lane];
    }
    uint64_t bridgeA = 0ull, bridgeB = 0ull;
    __syncthreads();

    for (int p = 0; p < 8; ++p) {
        if (wave == 0) {
            const int a = 2 * p, bw = 2 * p + 1;
            const uint64_t mda = dA, mdb = dB, msab = sAB;
            const uint64_t b2a = brA2, b2b = brB2, b3a = brA3, b3b = brB3;
            // prefetch phase p+1 operands (addresses independent of keeps)
            if (p < 7) {
                const int an = 2 * p + 2, bn = 2 * p + 3;
                dA  = Mg[(size_t)an * M_WSTRIDE + 64 * an + lane];
                dB  = Mg[(size_t)bn * M_WSTRIDE + 64 * bn + lane];
                sAB = Mg[(size_t)bn * M_WSTRIDE + 64 * an + lane];
                if (p < 6) {
                    const int a3 = 2 * p + 4, b3 = 2 * p + 5;
                    brA2 = Mg[(size_t)a3 * M_WSTRIDE + 64 * an + lane];
                    brB2 = Mg[(size_t)a3 * M_WSTRIDE + 64 * bn + lane];
                    brA3 = Mg[(size_t)b3 * M_WSTRIDE + 64 * an + lane];
                    brB3 = Mg[(size_t)b3 * M_WSTRIDE + 64 * bn + lane];
                }
            }
            // ---- word a (a <= 14, always fully valid) ----
            uint64_t curA = sfl64(remv[a]) | sfl64(bridgeA);
            {
                const uint64_t amS = sfl64(bfly_or64(mda));
                const uint64_t Q        = amS & ~curA;
                const uint64_t keptSure = ~curA & ~Q;
                curA |= sfl64(bfly_or64(((keptSure >> lane) & 1ull) ? mda : 0ull));
                uint64_t work = Q & ~curA;
                while (work) {
                    const int bp = (int)__builtin_ctzll(work);
                    curA |= bcast64(mda, bp);
                    work &= ~(1ull << bp);
                    work &= ~curA;
                }
            }
            const uint64_t keepA = ~curA;
            // in-phase bridge a -> bw
            const uint64_t sc = bfly_or64(((keepA >> lane) & 1ull) ? msab : 0ull);
            // ---- word bw ----
            const uint64_t validB = (bw == 15) ? ((1ull << 40) - 1ull) : ~0ull;
            uint64_t curB = sfl64(remv[bw]) | sfl64(bridgeB) | sfl64(sc);
            {
                const bool lv = (bw < 15) || (lane < 40);
                const uint64_t amS = sfl64(bfly_or64(lv ? mdb : 0ull));
                const uint64_t Q        = amS & ~curB & validB;
                const uint64_t keptSure = validB & ~curB & ~Q;
                curB |= sfl64(bfly_or64(((keptSure >> lane) & 1ull) ? mdb : 0ull));
                uint64_t work = Q & ~curB;
                while (work) {
                    const int bp = (int)__builtin_ctzll(work);
                    curB |= bcast64(mdb, bp);
                    work &= ~(1ull << bp);
                    work &= ~curB;
                }
            }
            const uint64_t keepB = (~curB) & validB;
            if (lane == 0) { keepW[a] = keepA; keepW[bw] = keepB; }
            // bridges for phase p+1 (u in {a,bw} -> v in {2p+2, 2p+3})
            if (p < 7) {
                bridgeA = bfly_or64((((keepA >> lane) & 1ull) ? b2a : 0ull) |
                                    (((keepB >> lane) & 1ull) ? b2b : 0ull));
                bridgeB = bfly_or64((((keepA >> lane) & 1ull) ? b3a : 0ull) |
                                    (((keepB >> lane) & 1ull) ? b3b : 0ull));
            }
        } else if (wave <= 6 && p >= 1 && p <= wave) {
            const int v1 = 2 * wave + 2, v2 = 2 * wave + 3;
            const uint64_t a1 = mA1, b1 = mB1, a2 = mA2, b2 = mB2;
            // prefetch phase p+1 operands: rows-blocks 2p, 2p+1
            if (p < wave) {
                mA1 = Mg[(size_t)v1 * M_WSTRIDE + 64 * (2 * p)     + lane];
                mB1 = Mg[(size_t)v1 * M_WSTRIDE + 64 * (2 * p + 1) + lane];
                mA2 = Mg[(size_t)v2 * M_WSTRIDE + 64 * (2 * p)     + lane];
                mB2 = Mg[(size_t)v2 * M_WSTRIDE + 64 * (2 * p + 1) + lane];
            }
            const uint64_t kmA = keepW[2 * p - 2];         // uniform
            const uint64_t kmB = keepW[2 * p - 1];         // uniform
            uint64_t x1 = (((kmA >> lane) & 1ull) ? a1 : 0ull) |
                          (((kmB >> lane) & 1ull) ? b1 : 0ull);
            x1 = bfly_or64(x1);
            uint64_t x2 = (((kmA >> lane) & 1ull) ? a2 : 0ull) |
                          (((kmB >> lane) & 1ull) ? b2 : 0ull);
            x2 = bfly_or64(x2);
            if (lane == 0) { remv[v1] |= x1; remv[v2] |= x2; }
        }
        __syncthreads();
    }

    if (t == 0) {
        uint32_t acc = 0u;
        for (int w = 0; w < 16; ++w) {
            wordPref[w] = acc;
            acc += (uint32_t)__popcll(keepW[w]);
        }
    }
    float* ob = out + (size_t)b * (POST_NMS * 4);
    for (int i = t; i < POST_NMS * 4; i += K3_NT) ob[i] = 0.0f;
    __syncthreads();

    for (int tt = t; tt < PRE_NMS; tt += K3_NT) {
        const int w = tt >> 6, bpos = tt & 63;
        uint64_t kw = keepW[w];
        if ((kw >> bpos) & 1ull) {
            uint32_t rank = wordPref[w] +
                            (uint32_t)__popcll(kw & ((1ull << bpos) - 1ull));
            if (rank < POST_NMS) {
                const float* wb = wsBox + (size_t)b * WS_BOX_FLOATS_PER_B;
                float* o = ob + (size_t)rank * 4;
                o[0] = clip01(wb[tt]);
                o[1] = clip01(wb[SEL_CAP + tt]);
                o[2] = clip01(wb[2*SEL_CAP + tt]);
                o[3] = clip01(wb[3*SEL_CAP + tt]);
            }
        }
    }
}

extern "C" void kernel_launch(void* const* d_in, const int* in_sizes, int n_in,
                              void* d_out, int out_size, void* d_ws, size_t ws_size,
                              hipStream_t stream) {
    const float* deltas  = (const float*)d_in[0];
    const float* labels  = (const float*)d_in[1];
    const float* anchors = (const float*)d_in[2];
    float* out = (float*)d_out;
    const int B = in_sizes[1] / N_ANCH;   // 16

    // ws: [cand (B,16,128) u64][box (B,5,1024) f32][M (B,16,1024) u64]
    char* p = (char*)d_ws;
    uint64_t* wsCand = (uint64_t*)p;
    float*    wsBox  = (float*)(p + (size_t)B * MERGE_CAP * 8);
    uint64_t* wsM    = (uint64_t*)(p + (size_t)B * MERGE_CAP * 8
                                     + (size_t)B * WS_BOX_FLOATS_PER_B * 4);

    k1s_slice_top<<<dim3(SLICES, B), K1_NT, 0, stream>>>(labels, wsCand);
    k1m_merge_decode<<<dim3(SLICES, B), K1_NT, 0, stream>>>(deltas, anchors, wsCand, wsBox);
    k2_iou_matrix<<<dim3(24, B), 1024, 0, stream>>>(wsBox, wsM);
    k3_reduce_out<<<B, K3_NT, 0, stream>>>(wsBox, wsM, out);
}